// Round 1
// baseline (732.693 us; speedup 1.0000x reference)
//
#include <hip/hip_runtime.h>
#include <cstdint>

// Problem: B=131072, D=256, C=1000
// out = [ logits[B,C] fp32 ; weight[C,D] fp32 ]
// logits[b,c] = -max(||xn_b||^2 + ||wn_c||^2 - 2*dot, 0) ; norms==1 -> min(2*dot-2, 0)

#define B_ROWS 131072
#define D_DIM 256
#define C_DIM 1000
#define C_PAD 1024
#define OUT_LOGITS ((size_t)B_ROWS * (size_t)C_DIM)

typedef __bf16 bf16x8 __attribute__((ext_vector_type(8)));
typedef float f32x4 __attribute__((ext_vector_type(4)));

typedef __attribute__((address_space(1))) void gbl_void;
typedef __attribute__((address_space(3))) void lds_void;

__device__ __forceinline__ void g2l16(const void* g, void* l) {
    // global -> LDS direct DMA, 16B per lane; LDS dest = wave-uniform base + lane*16
    __builtin_amdgcn_global_load_lds((gbl_void*)(uintptr_t)g,
                                     (lds_void*)(uint32_t)(uintptr_t)l, 16, 0, 0);
}

__device__ __forceinline__ unsigned short f2bf(float f) {
    unsigned int u = __builtin_bit_cast(unsigned int, f);
    u = (u + 0x7fffu + ((u >> 16) & 1u)) >> 16;  // RNE
    return (unsigned short)u;
}

// Normalize weight rows -> bf16 wn[C_PAD][256] (zero-pad rows >= 1000); copy weight -> out tail.
__global__ void prep_w(const float* __restrict__ w, unsigned short* __restrict__ wn,
                       float* __restrict__ out_tail) {
    int row = blockIdx.x * 4 + (threadIdx.x >> 6);
    int lane = threadIdx.x & 63;
    if (row < C_DIM) {
        float4 v = ((const float4*)(w + (size_t)row * D_DIM))[lane];
        float s = v.x * v.x + v.y * v.y + v.z * v.z + v.w * v.w;
#pragma unroll
        for (int off = 32; off; off >>= 1) s += __shfl_xor(s, off, 64);
        float inv = 1.0f / fmaxf(sqrtf(s), 1e-12f);
        ushort4 o = { f2bf(v.x * inv), f2bf(v.y * inv), f2bf(v.z * inv), f2bf(v.w * inv) };
        ((ushort4*)(wn + (size_t)row * D_DIM))[lane] = o;
        ((float4*)(out_tail + (size_t)row * D_DIM))[lane] = v;  // passthrough output
    } else {
        ushort4 z = { 0, 0, 0, 0 };
        ((ushort4*)(wn + (size_t)row * D_DIM))[lane] = z;
    }
}

// Normalize x rows -> bf16 xn[B][256]. One wave per row.
__global__ void prep_x(const float* __restrict__ x, unsigned short* __restrict__ xn) {
    int row = blockIdx.x * 4 + (threadIdx.x >> 6);
    int lane = threadIdx.x & 63;
    float4 v = ((const float4*)(x + (size_t)row * D_DIM))[lane];
    float s = v.x * v.x + v.y * v.y + v.z * v.z + v.w * v.w;
#pragma unroll
    for (int off = 32; off; off >>= 1) s += __shfl_xor(s, off, 64);
    float inv = 1.0f / fmaxf(sqrtf(s), 1e-12f);
    ushort4 o = { f2bf(v.x * inv), f2bf(v.y * inv), f2bf(v.z * inv), f2bf(v.w * inv) };
    ((ushort4*)(xn + (size_t)row * D_DIM))[lane] = o;
}

// NT GEMM: A=xn[B][256] bf16, Bt=wn[C_PAD][256] bf16; out logits fp32.
// 128x128 tile, BK=64 (4 k-chunks), 4 waves each computing 64x64 via 4x4 16x16x32 MFMA frags.
#define BM 128
#define BN 128

__global__ __launch_bounds__(256, 3) void gemm_logits(const unsigned short* __restrict__ A,
                                                      const unsigned short* __restrict__ Bt,
                                                      float* __restrict__ out) {
    // [128 rows][64 cols] bf16, row = 128B = 8 chunks of 16B; chunk slot s holds
    // global chunk s ^ (row&7)  (XOR swizzle to break 128B-stride bank conflicts)
    __shared__ __align__(16) unsigned short As[BM * 64];
    __shared__ __align__(16) unsigned short Bs[BN * 64];

    const int tid = threadIdx.x;
    const int w = tid >> 6;
    const int lane = tid & 63;
    const int m0 = blockIdx.y * BM;
    const int n0 = blockIdx.x * BN;

    const int wm = w >> 1, wn = w & 1;
    const int mfrag = lane & 15;
    const int quad = lane >> 4;

    const int l8 = lane >> 3;  // row within 8-row group
    const int l7 = lane & 7;   // 16B chunk id
    const int cg = l7 ^ l8;    // swizzled global chunk fetched by this lane

    const char* gA = (const char*)(A + (size_t)m0 * D_DIM);
    const char* gB = (const char*)(Bt + (size_t)n0 * D_DIM);

    f32x4 acc[4][4];
#pragma unroll
    for (int i = 0; i < 4; i++)
#pragma unroll
        for (int j = 0; j < 4; j++) acc[i][j] = { 0.f, 0.f, 0.f, 0.f };

#pragma unroll
    for (int kc = 0; kc < 4; kc++) {
#pragma unroll
        for (int i = 0; i < 4; i++) {
            const int inst = w * 4 + i;
            const int row = inst * 8 + l8;
            const long goff = (long)row * (D_DIM * 2) + kc * 128 + cg * 16;
            g2l16(gA + goff, (char*)As + inst * 1024);
            g2l16(gB + goff, (char*)Bs + inst * 1024);
        }
        __syncthreads();  // drains vmcnt(0): LDS tiles complete
#pragma unroll
        for (int ks = 0; ks < 2; ks++) {
            bf16x8 af[4], bq[4];
            const int slot = ((ks * 4 + quad) ^ (mfrag & 7)) * 16;
#pragma unroll
            for (int i = 0; i < 4; i++) {
                const int arow = wm * 64 + i * 16 + mfrag;
                af[i] = *(const bf16x8*)((const char*)As + arow * 128 + slot);
                const int brow = wn * 64 + i * 16 + mfrag;
                bq[i] = *(const bf16x8*)((const char*)Bs + brow * 128 + slot);
            }
#pragma unroll
            for (int i = 0; i < 4; i++)
#pragma unroll
                for (int j = 0; j < 4; j++)
                    acc[i][j] = __builtin_amdgcn_mfma_f32_16x16x32_bf16(af[i], bq[j], acc[i][j], 0, 0, 0);
        }
        __syncthreads();
    }

    // Epilogue: C/D layout col = lane&15, row = quad*4 + reg
    const int colbase = n0 + wn * 64 + mfrag;
    const int rowbase = m0 + wm * 64 + quad * 4;
#pragma unroll
    for (int j = 0; j < 4; j++) {
        const int col = colbase + j * 16;
        if (col < C_DIM) {
#pragma unroll
            for (int i = 0; i < 4; i++) {
                const int row = rowbase + i * 16;
#pragma unroll
                for (int t = 0; t < 4; t++) {
                    out[(size_t)(row + t) * C_DIM + col] = fminf(2.0f * acc[i][j][t] - 2.0f, 0.0f);
                }
            }
        }
    }
}

extern "C" void kernel_launch(void* const* d_in, const int* in_sizes, int n_in,
                              void* d_out, int out_size, void* d_ws, size_t ws_size,
                              hipStream_t stream) {
    const float* x = (const float*)d_in[0];
    const float* w = (const float*)d_in[1];
    float* out = (float*)d_out;

    // workspace: xn bf16 [B][256] (64 MiB) then wn bf16 [1024][256] (512 KiB)
    unsigned short* xn = (unsigned short*)d_ws;
    unsigned short* wn = xn + (size_t)B_ROWS * D_DIM;

    prep_w<<<C_PAD / 4, 256, 0, stream>>>(w, wn, out + OUT_LOGITS);
    prep_x<<<B_ROWS / 4, 256, 0, stream>>>(x, xn);
    dim3 grid(C_PAD / BN, B_ROWS / BM);  // (8, 1024): n fastest -> per-XCD B residency
    gemm_logits<<<grid, 256, 0, stream>>>(xn, wn, out);
}